// Round 1
// baseline (1211.514 us; speedup 1.0000x reference)
//
#include <hip/hip_runtime.h>
#include <hip/hip_bf16.h>
#include <cstdint>
#include <cstddef>

// Problem constants (B=batch, P=patches, C=channels/d_model)
#define BB 1024
#define PP 64
#define CC 512

constexpr int CT = 8;    // channels per block (1 per wave, 8 waves)
constexpr int BT = 64;   // batches per block (1 per lane)
constexpr float LN_EPS = 1e-5f;

// ---------------- LDS map (50176 B total, kept < 64 KiB) ----------------
// Phase A (x staging, one p-half at a time):
//   ushort xs[CT][BT][40]   (32 valid p + 8 pad; rows 80 B, 16 B aligned) = 40960 B
// Phase B (after xr regs loaded; overlaps/reuses the same memory):
//   float ssum[64q][64b] @ 0      (16384 B)
//   float ssq [64q][64b] @ 16384  (16384 B)
//   float R   [64b][68]  @ 32768  (17408 B)  res-staging, 8-q chunks, pad 68 breaks bank alias

__device__ __forceinline__ float bf2f(unsigned short h) {
    union { unsigned int u; float f; } v; v.u = ((unsigned int)h) << 16; return v.f;
}
__device__ __forceinline__ unsigned short f2bf(float f) {
    union { float f; unsigned int u; } v; v.f = f;
    unsigned int r = v.u + 0x7fffu + ((v.u >> 16) & 1u);   // RNE, inputs finite
    return (unsigned short)(r >> 16);
}

__global__ __launch_bounds__(512) void k_mix(
    const float* __restrict__ X,  const float* __restrict__ W1,
    const float* __restrict__ B1, const float* __restrict__ W2,
    const float* __restrict__ B2, float* __restrict__ OUT,
    float* __restrict__ gsum, float* __restrict__ gsq)
{
    __shared__ __align__(16) unsigned char lds[50176];
    unsigned short* xs = (unsigned short*)lds;
    float* ssum = (float*)lds;                  // [64q][64b]
    float* ssq  = (float*)(lds + 16384);
    float* R    = (float*)(lds + 32768);        // [64b][68]

    const int tid  = threadIdx.x;
    const int lane = tid & 63;                       // batch lane
    const int wv   = __builtin_amdgcn_readfirstlane(tid >> 6);  // wave id -> channel (forced uniform)
    const int c0   = blockIdx.x * CT;
    const int b0   = blockIdx.y * BT;
    const int c    = c0 + wv;

    float xr[64];  // this thread's x[b0+lane, p, c] (bf16-rounded), later holds res[q]

    // ---- stage x through LDS transpose, two p-halves (keeps LDS small) ----
    #pragma unroll
    for (int ph = 0; ph < 2; ++ph) {
        // 4096 float4 quads: fi bits [0]=c4(2) [5:1]=p(32) [11:6]=b(64)
        // consecutive lanes cover 32 B contiguous (c4 fastest) -> L2 merges across
        // co-resident c-neighbor blocks (gridDim.x fastest = all c-groups per b-group)
        #pragma unroll
        for (int it = 0; it < 8; ++it) {
            int fi = it * 512 + tid;
            int c4 = fi & 1;
            int p  = (fi >> 1) & 31;
            int b  = fi >> 6;
            const float4 v = *(const float4*)(X + ((size_t)(b0 + b) * PP + (ph * 32 + p)) * CC + c0 + c4 * 4);
            int o0 = (c4 * 4) * (BT * 40) + b * 40 + p;
            xs[o0               ] = f2bf(v.x);
            xs[o0 + 1 * BT * 40 ] = f2bf(v.y);
            xs[o0 + 2 * BT * 40 ] = f2bf(v.z);
            xs[o0 + 3 * BT * 40 ] = f2bf(v.w);
        }
        __syncthreads();
        const unsigned short* row = xs + wv * (BT * 40) + lane * 40;
        #pragma unroll
        for (int i = 0; i < 32; ++i) xr[ph * 32 + i] = bf2f(row[i]);
        __syncthreads();   // before next half (or stats zeroing) overwrites region
    }

    // ---- zero LDS stats (region overlaps xs; xr regs already loaded) ----
    {
        float* z = (float*)lds;
        #pragma unroll
        for (int i = 0; i < 16; ++i) z[i * 512 + tid] = 0.0f;   // 8192 floats = ssum+ssq
    }
    __syncthreads();

    // Wave-uniform weight/bias pointers -> scalar-load candidates
    const float* __restrict__ w1c = W1 + (size_t)c * (PP * PP);
    const float* __restrict__ w2c = W2 + (size_t)c * (PP * PP);
    const float* __restrict__ b1c = B1 + (size_t)c * PP;
    const float* __restrict__ b2c = B2 + (size_t)c * PP;

    // ---- layer 1: h[q] = gelu( sum_p W1[c,q,p] * x[p] + b1[c,q] ) ----
    float hr[64];
    #pragma unroll
    for (int q = 0; q < 64; ++q) {
        float a0 = b1c[q], a1 = 0.f, a2 = 0.f, a3 = 0.f;  // 4 accs break dep chain
        #pragma unroll
        for (int p4 = 0; p4 < 16; ++p4) {
            const float4 w = *(const float4*)(w1c + q * 64 + p4 * 4);
            a0 += w.x * xr[p4 * 4 + 0];
            a1 += w.y * xr[p4 * 4 + 1];
            a2 += w.z * xr[p4 * 4 + 2];
            a3 += w.w * xr[p4 * 4 + 3];
        }
        float t = (a0 + a2) + (a1 + a3);
        // tanh-form GELU == t * sigmoid(2*0.79788456*(t + 0.044715 t^3));
        // max |dev| from exact erf-GELU ~3e-3 << 0.11 threshold
        float s = 1.5957691216f * (t + 0.044715f * t * t * t);
        hr[q] = t / (1.0f + __expf(-s));
    }

    // ---- layer 2 + residual + LN partial stats ----
    #pragma unroll
    for (int q = 0; q < 64; ++q) {
        float a0 = b2c[q], a1 = 0.f, a2 = 0.f, a3 = 0.f;
        #pragma unroll
        for (int p4 = 0; p4 < 16; ++p4) {
            const float4 w = *(const float4*)(w2c + q * 64 + p4 * 4);
            a0 += w.x * hr[p4 * 4 + 0];
            a1 += w.y * hr[p4 * 4 + 1];
            a2 += w.z * hr[p4 * 4 + 2];
            a3 += w.w * hr[p4 * 4 + 3];
        }
        float r = ((a0 + a2) + (a1 + a3)) + xr[q];
        xr[q] = r;                                   // xr[q] dead after residual -> reuse for res
        atomicAdd(&ssum[q * 64 + lane], r);          // ds_add_f32, 2-way bank alias = free
        atomicAdd(&ssq [q * 64 + lane], r * r);
    }
    __syncthreads();

    // ---- flush block-partial LN stats (8-ch partial per (b,q)) to global ----
    #pragma unroll
    for (int i = 0; i < 8; ++i) {
        int idx = i * 512 + tid;                     // 4096 (q,b) pairs
        int q = idx >> 6, b = idx & 63;
        int m = (b0 + b) * PP + q;
        atomicAdd(&gsum[m], ssum[idx]);
        atomicAdd(&gsq [m], ssq [idx]);
    }

    // ---- res write: stage through LDS -> 32 B-granule coalesced stores ----
    #pragma unroll
    for (int ch = 0; ch < 8; ++ch) {
        #pragma unroll
        for (int j = 0; j < 8; ++j)
            R[lane * 68 + j * 8 + wv] = xr[ch * 8 + j];
        __syncthreads();
        {
            int b = tid >> 3, jq = tid & 7;          // 512 (b,jq) pairs, 1 per thread
            const float4* src = (const float4*)(R + b * 68 + jq * 8);  // 16B aligned
            float4 v0 = src[0], v1 = src[1];
            size_t m = (size_t)(b0 + b) * PP + (ch * 8 + jq);
            float4* dst = (float4*)(OUT + m * CC + c0);
            dst[0] = v0; dst[1] = v1;
        }
        __syncthreads();   // before next chunk overwrites R
    }
}

// In-place LayerNorm over channels using the precomputed stats.
__global__ __launch_bounds__(256) void k_ln(
    float* __restrict__ OUT, const float* __restrict__ gsum, const float* __restrict__ gsq,
    const float* __restrict__ gamma, const float* __restrict__ beta)
{
    const int lane = threadIdx.x & 63;
    const int w    = threadIdx.x >> 6;
    const int m    = blockIdx.x * 4 + w;             // row over B*P = 65536
    float4* row = (float4*)(OUT + (size_t)m * CC);
    const float4* g4 = (const float4*)gamma;
    const float4* be4 = (const float4*)beta;
    float mu  = gsum[m] * (1.0f / CC);
    float var = gsq[m] * (1.0f / CC) - mu * mu;
    float inv = rsqrtf(var + LN_EPS);
    #pragma unroll
    for (int h = 0; h < 2; ++h) {
        int j = lane + h * 64;                       // 128 float4 per row
        float4 v = row[j], g = g4[j], bb = be4[j];
        v.x = (v.x - mu) * inv * g.x + bb.x;
        v.y = (v.y - mu) * inv * g.y + bb.y;
        v.z = (v.z - mu) * inv * g.z + bb.z;
        v.w = (v.w - mu) * inv * g.w + bb.w;
        row[j] = v;
    }
}

extern "C" void kernel_launch(void* const* d_in, const int* in_sizes, int n_in,
                              void* d_out, int out_size, void* d_ws, size_t ws_size,
                              hipStream_t stream) {
    const float* X  = (const float*)d_in[0];
    const float* W1 = (const float*)d_in[1];
    const float* B1 = (const float*)d_in[2];
    const float* W2 = (const float*)d_in[3];
    const float* B2 = (const float*)d_in[4];
    const float* G  = (const float*)d_in[5];
    const float* Be = (const float*)d_in[6];
    float* OUT  = (float*)d_out;
    float* gsum = (float*)d_ws;                      // [B*P] fp32
    float* gsq  = gsum + (size_t)BB * PP;            // [B*P] fp32  (512 KiB total in ws)

    hipMemsetAsync(d_ws, 0, (size_t)BB * PP * 2 * sizeof(float), stream);

    dim3 g1(CC / CT, BB / BT);                       // (64, 16): c-groups fastest -> co-resident for L2 merge
    k_mix<<<g1, 512, 0, stream>>>(X, W1, B1, W2, B2, OUT, gsum, gsq);
    k_ln<<<(BB * PP) / 4, 256, 0, stream>>>(OUT, gsum, gsq, G, Be);
}